// Round 4
// baseline (333.198 us; speedup 1.0000x reference)
//
#include <hip/hip_runtime.h>
#include <stdint.h>

typedef __attribute__((ext_vector_type(4))) int   v4i;
typedef __attribute__((ext_vector_type(8))) int   v8i;
typedef __attribute__((ext_vector_type(4))) float v4f;

#define BATCH 8192
#define KDIM  4096
#define NOUT  4096
#define KB    (KDIM / 2)     // bytes per packed fp4 row = 2048
#define BK_B  128            // K-tile bytes per row = 256 fp4 elems
#define NT    (KDIM / 256)   // 16 K-tiles

// pack x: fp32 -> fp4 e2m1 {x>0 -> 1.0 (0x2), else 0.0 (0x0)}, 8 elems/thread
__global__ __launch_bounds__(256) void pack_x4(const float* __restrict__ x,
                                               uint32_t* __restrict__ xb) {
    int t = blockIdx.x * 256 + threadIdx.x;
    const float4* p = (const float4*)x + (size_t)t * 2;
    float4 f0 = p[0];
    float4 f1 = p[1];
    uint32_t b = (f0.x > 0.f ? 0x2u        : 0u)
               | (f0.y > 0.f ? 0x20u       : 0u)
               | (f0.z > 0.f ? 0x200u      : 0u)
               | (f0.w > 0.f ? 0x2000u     : 0u)
               | (f1.x > 0.f ? 0x20000u    : 0u)
               | (f1.y > 0.f ? 0x200000u   : 0u)
               | (f1.z > 0.f ? 0x2000000u  : 0u)
               | (f1.w > 0.f ? 0x20000000u : 0u);
    xb[t] = b;
}

// pack W: fp32 -> fp4 e2m1 {W>0 -> +1.0 (0x2), else -1.0 (0xA)}, 8 elems/thread
__global__ __launch_bounds__(256) void pack_w4(const float* __restrict__ w,
                                               uint32_t* __restrict__ wb) {
    int t = blockIdx.x * 256 + threadIdx.x;
    const float4* p = (const float4*)w + (size_t)t * 2;
    float4 f0 = p[0];
    float4 f1 = p[1];
    uint32_t b = (f0.x > 0.f ? 0x2u        : 0xAu)
               | (f0.y > 0.f ? 0x20u       : 0xA0u)
               | (f0.z > 0.f ? 0x200u      : 0xA00u)
               | (f0.w > 0.f ? 0x2000u     : 0xA000u)
               | (f1.x > 0.f ? 0x20000u    : 0xA0000u)
               | (f1.y > 0.f ? 0x200000u   : 0xA00000u)
               | (f1.z > 0.f ? 0x2000000u  : 0xA000000u)
               | (f1.w > 0.f ? 0x20000000u : 0xA0000000u);
    wb[t] = b;
}

// C[M,N] = A[M,K] * B[N,K]^T, fp4 e2m1 (values {0,1} x {-1,+1}), f32 out —
// integer-exact via unit MX scales.
// 256x256 tile, 8 waves (2M x 4N), per-wave 128x64, BK = 256 fp4 = 128 B/row.
// 8-phase schedule (T3+T4+T5): per K-tile, 4 phases of
//   {ds_read subtile -> s_barrier -> lgkmcnt(0) -> setprio(1) 16 MFMA
//    setprio(0) -> s_barrier}
// Counted s_waitcnt vmcnt(8) ONCE per tile (top) keeps the next tile's 8
// global_load_lds in flight ACROSS barriers; stage of tile t+2 issued after
// phase-3's closing barrier (buffer provably dead: every wave's lgkmcnt(0)
// retired its reads before that barrier). Last tile peeled with vmcnt(0).
// LDS chunk XOR swizzle via pre-swizzled GLOBAL source: row r slot s holds
// global chunk s ^ (r&7); read slot for chunk c of row r is c ^ (r&7).
__global__ __launch_bounds__(512, 2) void bin_gemm4(const uint8_t* __restrict__ A,
                                                    const uint8_t* __restrict__ B,
                                                    float* __restrict__ C) {
    // [buf][A: 32 KiB | B: 32 KiB] x 2 = 128 KiB
    __shared__ __align__(16) uint8_t sm[131072];

    const int tid  = threadIdx.x;
    const int w    = tid >> 6;          // wave 0..7
    const int lane = tid & 63;
    const int q    = lane >> 4;         // quad -> 16B chunk within 64B k-slice
    const int mp   = lane & 15;

    const int Mbase = blockIdx.y * 256;
    const int Nbase = blockIdx.x * 256;
    const int wm = (w >> 2) * 128;      // wave M offset in tile
    const int wn = (w & 3) * 64;        // wave N offset in tile

    // Staging: one global_load_lds writes LDS base + lane*16 (1 KiB/wave-instr).
    // Lane covers row L*64 + w*8 + (lane>>3), slot lane&7; fetch global chunk
    // (lane&7) ^ ((lane>>3)&7)  (srow base rows are %8 == 0).
    const int srow = w * 8 + (lane >> 3);
    const int swz  = ((lane & 7) ^ ((lane >> 3) & 7)) * 16;

    const uint8_t* pA = A + (size_t)(Mbase + srow) * KB + swz;
    const uint8_t* pB = B + (size_t)(Nbase + srow) * KB + swz;
    const int ldsw = w * 1024;          // wave-uniform LDS chunk base

    const int rsw = mp & 7;             // frag rows all have (row & 7) == mp & 7

    v4f acc[8][4] = {};

    // ---- prologue: stage tiles 0 and 1 (8 loads each) ----
    #pragma unroll
    for (int L = 0; L < 4; ++L) {
        __builtin_amdgcn_global_load_lds(
            (__attribute__((address_space(1))) void*)(pA + (size_t)(L * 64) * KB),
            (__attribute__((address_space(3))) void*)(sm + L * 8192 + ldsw), 16, 0, 0);
        __builtin_amdgcn_global_load_lds(
            (__attribute__((address_space(1))) void*)(pB + (size_t)(L * 64) * KB),
            (__attribute__((address_space(3))) void*)(sm + 32768 + L * 8192 + ldsw), 16, 0, 0);
    }
    #pragma unroll
    for (int L = 0; L < 4; ++L) {
        __builtin_amdgcn_global_load_lds(
            (__attribute__((address_space(1))) void*)(pA + (size_t)(L * 64) * KB + BK_B),
            (__attribute__((address_space(3))) void*)(sm + 65536 + L * 8192 + ldsw), 16, 0, 0);
        __builtin_amdgcn_global_load_lds(
            (__attribute__((address_space(1))) void*)(pB + (size_t)(L * 64) * KB + BK_B),
            (__attribute__((address_space(3))) void*)(sm + 65536 + 32768 + L * 8192 + ldsw), 16, 0, 0);
    }

    for (int t = 0; t < NT - 1; ++t) {
        // tile t landed (oldest 8 of <=16 outstanding); t+1 stays in flight
        asm volatile("s_waitcnt vmcnt(8)" ::: "memory");
        __builtin_amdgcn_s_barrier();

        const uint8_t* sA = sm + (t & 1) * 65536;
        const uint8_t* sB = sA + 32768;

        v4i bfr[4][2];
        #pragma unroll
        for (int p = 0; p < 4; ++p) {
            if (p == 0) {
                #pragma unroll
                for (int ni = 0; ni < 4; ++ni)
                    #pragma unroll
                    for (int ks = 0; ks < 2; ++ks)
                        bfr[ni][ks] = *(const v4i*)(sB + (wn + ni * 16 + mp) * 128
                                                    + ((ks * 4 + q) ^ rsw) * 16);
            }
            v4i afr[2][2];
            #pragma unroll
            for (int i = 0; i < 2; ++i)
                #pragma unroll
                for (int ks = 0; ks < 2; ++ks)
                    afr[i][ks] = *(const v4i*)(sA + (wm + (p * 2 + i) * 16 + mp) * 128
                                               + ((ks * 4 + q) ^ rsw) * 16);

            __builtin_amdgcn_s_barrier();
            asm volatile("s_waitcnt lgkmcnt(0)" ::: "memory");
            __builtin_amdgcn_s_setprio(1);
            #pragma unroll
            for (int i = 0; i < 2; ++i)
                #pragma unroll
                for (int ni = 0; ni < 4; ++ni)
                    #pragma unroll
                    for (int ks = 0; ks < 2; ++ks) {
                        v8i a8 = {afr[i][ks][0], afr[i][ks][1], afr[i][ks][2], afr[i][ks][3],
                                  0, 0, 0, 0};
                        v8i b8 = {bfr[ni][ks][0], bfr[ni][ks][1], bfr[ni][ks][2],
                                  bfr[ni][ks][3], 0, 0, 0, 0};
                        acc[p * 2 + i][ni] = __builtin_amdgcn_mfma_scale_f32_16x16x128_f8f6f4(
                            a8, b8, acc[p * 2 + i][ni], 4, 4,
                            0, 0x7F7F7F7F, 0, 0x7F7F7F7F);
                    }
            __builtin_amdgcn_s_setprio(0);
            __builtin_amdgcn_s_barrier();
        }

        // buf[t&1] is dead (every wave's reads retired before the barrier
        // above) — issue tile t+2's 8 loads into it; they stay in flight
        // through tile t+1's phases.
        if (t < NT - 2) {
            const int kof = (t + 2) * BK_B;
            uint8_t* db = (uint8_t*)sm + (t & 1) * 65536;
            #pragma unroll
            for (int L = 0; L < 4; ++L) {
                __builtin_amdgcn_global_load_lds(
                    (__attribute__((address_space(1))) void*)(pA + (size_t)(L * 64) * KB + kof),
                    (__attribute__((address_space(3))) void*)(db + L * 8192 + ldsw), 16, 0, 0);
                __builtin_amdgcn_global_load_lds(
                    (__attribute__((address_space(1))) void*)(pB + (size_t)(L * 64) * KB + kof),
                    (__attribute__((address_space(3))) void*)(db + 32768 + L * 8192 + ldsw), 16, 0, 0);
            }
        }
    }

    // ---- peeled last tile: full drain, no stage ----
    asm volatile("s_waitcnt vmcnt(0)" ::: "memory");
    __builtin_amdgcn_s_barrier();
    {
        const uint8_t* sA = sm + ((NT - 1) & 1) * 65536;
        const uint8_t* sB = sA + 32768;

        v4i bfr[4][2];
        #pragma unroll
        for (int p = 0; p < 4; ++p) {
            if (p == 0) {
                #pragma unroll
                for (int ni = 0; ni < 4; ++ni)
                    #pragma unroll
                    for (int ks = 0; ks < 2; ++ks)
                        bfr[ni][ks] = *(const v4i*)(sB + (wn + ni * 16 + mp) * 128
                                                    + ((ks * 4 + q) ^ rsw) * 16);
            }
            v4i afr[2][2];
            #pragma unroll
            for (int i = 0; i < 2; ++i)
                #pragma unroll
                for (int ks = 0; ks < 2; ++ks)
                    afr[i][ks] = *(const v4i*)(sA + (wm + (p * 2 + i) * 16 + mp) * 128
                                               + ((ks * 4 + q) ^ rsw) * 16);

            __builtin_amdgcn_s_barrier();
            asm volatile("s_waitcnt lgkmcnt(0)" ::: "memory");
            __builtin_amdgcn_s_setprio(1);
            #pragma unroll
            for (int i = 0; i < 2; ++i)
                #pragma unroll
                for (int ni = 0; ni < 4; ++ni)
                    #pragma unroll
                    for (int ks = 0; ks < 2; ++ks) {
                        v8i a8 = {afr[i][ks][0], afr[i][ks][1], afr[i][ks][2], afr[i][ks][3],
                                  0, 0, 0, 0};
                        v8i b8 = {bfr[ni][ks][0], bfr[ni][ks][1], bfr[ni][ks][2],
                                  bfr[ni][ks][3], 0, 0, 0, 0};
                        acc[p * 2 + i][ni] = __builtin_amdgcn_mfma_scale_f32_16x16x128_f8f6f4(
                            a8, b8, acc[p * 2 + i][ni], 4, 4,
                            0, 0x7F7F7F7F, 0, 0x7F7F7F7F);
                    }
            __builtin_amdgcn_s_setprio(0);
            __builtin_amdgcn_s_barrier();
        }
    }

    // C/D layout (shape-determined): col = lane&15, row = quad*4 + reg.
    float* Cp = C + (size_t)(Mbase + wm + q * 4) * NOUT + (Nbase + wn + mp);
    #pragma unroll
    for (int mi = 0; mi < 8; ++mi)
        #pragma unroll
        for (int ni = 0; ni < 4; ++ni)
            #pragma unroll
            for (int r = 0; r < 4; ++r)
                Cp[(size_t)(mi * 16 + r) * NOUT + ni * 16] = acc[mi][ni][r];
}

extern "C" void kernel_launch(void* const* d_in, const int* in_sizes, int n_in,
                              void* d_out, int out_size, void* d_ws, size_t ws_size,
                              hipStream_t stream) {
    const float* x = (const float*)d_in[0];   // [8192, 4096] f32
    const float* W = (const float*)d_in[1];   // [4096, 4096] f32, values +/-1
    float* out = (float*)d_out;               // [8192, 4096] f32

    uint8_t* xb = (uint8_t*)d_ws;                              // 16 MiB
    uint8_t* wb = (uint8_t*)d_ws + (size_t)BATCH * KDIM / 2;   // 8 MiB (24 MiB ws)

    pack_x4<<<(BATCH * (size_t)KDIM / 8) / 256, 256, 0, stream>>>(x, (uint32_t*)xb);
    pack_w4<<<((size_t)NOUT * KDIM / 8) / 256, 256, 0, stream>>>(W, (uint32_t*)wb);

    dim3 grid(NOUT / 256, BATCH / 256);   // (16, 32) = 512 blocks
    bin_gemm4<<<grid, 512, 0, stream>>>(xb, wb, out);
}

// Round 5
// 324.459 us; speedup vs baseline: 1.0269x; 1.0269x over previous
//
#include <hip/hip_runtime.h>
#include <stdint.h>

typedef __attribute__((ext_vector_type(4)))  int   v4i;
typedef __attribute__((ext_vector_type(8)))  int   v8i;
typedef __attribute__((ext_vector_type(16))) float v16f;

#define BATCH 8192
#define KDIM  4096
#define NOUT  4096
#define KB    (KDIM / 2)     // bytes per packed fp4 row = 2048
#define BK_B  128            // K-tile bytes per row = 256 fp4 elems
#define NT    (KDIM / 256)   // 16 K-tiles

// pack x: fp32 -> fp4 e2m1 {x>0 -> 1.0 (0x2), else 0.0 (0x0)}, 8 elems/thread
__global__ __launch_bounds__(256) void pack_x4(const float* __restrict__ x,
                                               uint32_t* __restrict__ xb) {
    int t = blockIdx.x * 256 + threadIdx.x;
    const float4* p = (const float4*)x + (size_t)t * 2;
    float4 f0 = p[0];
    float4 f1 = p[1];
    uint32_t b = (f0.x > 0.f ? 0x2u        : 0u)
               | (f0.y > 0.f ? 0x20u       : 0u)
               | (f0.z > 0.f ? 0x200u      : 0u)
               | (f0.w > 0.f ? 0x2000u     : 0u)
               | (f1.x > 0.f ? 0x20000u    : 0u)
               | (f1.y > 0.f ? 0x200000u   : 0u)
               | (f1.z > 0.f ? 0x2000000u  : 0u)
               | (f1.w > 0.f ? 0x20000000u : 0u);
    xb[t] = b;
}

// pack W: fp32 -> fp4 e2m1 {W>0 -> +1.0 (0x2), else -1.0 (0xA)}, 8 elems/thread
__global__ __launch_bounds__(256) void pack_w4(const float* __restrict__ w,
                                               uint32_t* __restrict__ wb) {
    int t = blockIdx.x * 256 + threadIdx.x;
    const float4* p = (const float4*)w + (size_t)t * 2;
    float4 f0 = p[0];
    float4 f1 = p[1];
    uint32_t b = (f0.x > 0.f ? 0x2u        : 0xAu)
               | (f0.y > 0.f ? 0x20u       : 0xA0u)
               | (f0.z > 0.f ? 0x200u      : 0xA00u)
               | (f0.w > 0.f ? 0x2000u     : 0xA000u)
               | (f1.x > 0.f ? 0x20000u    : 0xA0000u)
               | (f1.y > 0.f ? 0x200000u   : 0xA00000u)
               | (f1.z > 0.f ? 0x2000000u  : 0xA000000u)
               | (f1.w > 0.f ? 0x20000000u : 0xA0000000u);
    wb[t] = b;
}

// C[M,N] = A[M,K] * B[N,K]^T, fp4 e2m1 (values {0,1} x {-1,+1}), f32 out —
// integer-exact via unit MX scales.
// 256x256 tile, 8 waves (2M x 4N), per-wave 128x64, BK = 256 fp4 = 128 B/row.
// R3's 2-phase structure (best measured): per K-tile,
//   STAGE(next tile) -> ds_read + MFMA(current) -> __syncthreads().
// MFMA: 32x32x64 f8f6f4-fp4 (9099 TF ceiling vs 7228 for 16x16x128; half the
// instruction count at identical LDS traffic — 24 ds_read_b128/wave/tile).
// Fragment layout: A row = lane&31, k-chunk = lane>>5 (16 B/lane) — analog of
// the verified 16x16x128 mapping; B symmetric (col = lane&31).
// C/D: col = lane&31, row = (reg&3) + 8*(reg>>2) + 4*(lane>>5)  [m74/m101].
// LDS chunk XOR swizzle via pre-swizzled GLOBAL source: row r slot s holds
// global chunk s ^ (r&7); read slot for chunk c of row r is c ^ (r&7).
__global__ __launch_bounds__(512, 2) void bin_gemm4(const uint8_t* __restrict__ A,
                                                    const uint8_t* __restrict__ B,
                                                    float* __restrict__ C) {
    // [buf][A: 32 KiB | B: 32 KiB] x 2 = 128 KiB
    __shared__ __align__(16) uint8_t sm[131072];

    const int tid  = threadIdx.x;
    const int w    = tid >> 6;          // wave 0..7
    const int lane = tid & 63;
    const int l31  = lane & 31;         // fragment row / output col
    const int kc   = lane >> 5;         // k-chunk (16B) within 32B k-slice
    const int rsw  = lane & 7;          // (frag row) & 7, for swizzle readback

    const int Mbase = blockIdx.y * 256;
    const int Nbase = blockIdx.x * 256;
    const int wm = (w >> 2) * 128;      // wave M offset in tile
    const int wn = (w & 3) * 64;        // wave N offset in tile

    // Staging: one global_load_lds writes LDS base + lane*16 (1 KiB/wave-instr).
    // Lane covers row L*64 + w*8 + (lane>>3), slot lane&7; fetch global chunk
    // (lane&7) ^ ((lane>>3)&7)  (srow base rows are %8 == 0).
    const int srow = w * 8 + (lane >> 3);
    const int swz  = ((lane & 7) ^ ((lane >> 3) & 7)) * 16;

    const uint8_t* pA = A + (size_t)(Mbase + srow) * KB + swz;
    const uint8_t* pB = B + (size_t)(Nbase + srow) * KB + swz;
    const int ldsw = w * 1024;          // wave-uniform LDS chunk base

    v16f acc[4][2] = {};

    // ---- prologue: stage tile 0 into buf 0, drain ----
    #pragma unroll
    for (int L = 0; L < 4; ++L) {
        __builtin_amdgcn_global_load_lds(
            (__attribute__((address_space(1))) void*)(pA + (size_t)(L * 64) * KB),
            (__attribute__((address_space(3))) void*)(sm + L * 8192 + ldsw), 16, 0, 0);
        __builtin_amdgcn_global_load_lds(
            (__attribute__((address_space(1))) void*)(pB + (size_t)(L * 64) * KB),
            (__attribute__((address_space(3))) void*)(sm + 32768 + L * 8192 + ldsw), 16, 0, 0);
    }
    __syncthreads();

    for (int t = 0; t < NT; ++t) {
        // ---- issue next tile's 8 loads FIRST (overlap with compute) ----
        if (t + 1 < NT) {
            const int nbuf = (t + 1) & 1;
            const int kof  = (t + 1) * BK_B;
            #pragma unroll
            for (int L = 0; L < 4; ++L) {
                __builtin_amdgcn_global_load_lds(
                    (__attribute__((address_space(1))) void*)(pA + (size_t)(L * 64) * KB + kof),
                    (__attribute__((address_space(3))) void*)(sm + nbuf * 65536 + L * 8192 + ldsw),
                    16, 0, 0);
                __builtin_amdgcn_global_load_lds(
                    (__attribute__((address_space(1))) void*)(pB + (size_t)(L * 64) * KB + kof),
                    (__attribute__((address_space(3))) void*)(sm + nbuf * 65536 + 32768 + L * 8192 + ldsw),
                    16, 0, 0);
            }
        }

        // ---- compute current tile: 24 ds_read_b128 + 32 MFMA (32x32x64) ----
        const uint8_t* sA = sm + (t & 1) * 65536;
        const uint8_t* sB = sA + 32768;

        #pragma unroll
        for (int ks = 0; ks < 4; ++ks) {
            v4i bf[2];
            #pragma unroll
            for (int nb = 0; nb < 2; ++nb)
                bf[nb] = *(const v4i*)(sB + (wn + nb * 32 + l31) * 128
                                       + ((ks * 2 + kc) ^ rsw) * 16);
            #pragma unroll
            for (int mb = 0; mb < 4; ++mb) {
                v4i af = *(const v4i*)(sA + (wm + mb * 32 + l31) * 128
                                       + ((ks * 2 + kc) ^ rsw) * 16);
                v8i a8 = {af[0], af[1], af[2], af[3], 0, 0, 0, 0};
                #pragma unroll
                for (int nb = 0; nb < 2; ++nb) {
                    v8i b8 = {bf[nb][0], bf[nb][1], bf[nb][2], bf[nb][3], 0, 0, 0, 0};
                    acc[mb][nb] = __builtin_amdgcn_mfma_scale_f32_32x32x64_f8f6f4(
                        a8, b8, acc[mb][nb], 4, 4,
                        0, 0x7F7F7F7F, 0, 0x7F7F7F7F);
                }
            }
        }

        // one barrier per K-tile: drains this iter's loads (landed under
        // compute) + covers write-after-read for the buffer swap
        __syncthreads();
    }

    // C/D layout (shape-determined): col = lane&31,
    // row = (reg&3) + 8*(reg>>2) + 4*(lane>>5).
    float* Cp = C + (size_t)(Mbase + wm + 4 * kc) * NOUT + (Nbase + wn + l31);
    #pragma unroll
    for (int mb = 0; mb < 4; ++mb)
        #pragma unroll
        for (int nb = 0; nb < 2; ++nb)
            #pragma unroll
            for (int r = 0; r < 16; ++r)
                Cp[(size_t)(mb * 32 + (r & 3) + 8 * (r >> 2)) * NOUT + nb * 32]
                    = acc[mb][nb][r];
}

extern "C" void kernel_launch(void* const* d_in, const int* in_sizes, int n_in,
                              void* d_out, int out_size, void* d_ws, size_t ws_size,
                              hipStream_t stream) {
    const float* x = (const float*)d_in[0];   // [8192, 4096] f32
    const float* W = (const float*)d_in[1];   // [4096, 4096] f32, values +/-1
    float* out = (float*)d_out;               // [8192, 4096] f32

    uint8_t* xb = (uint8_t*)d_ws;                              // 16 MiB
    uint8_t* wb = (uint8_t*)d_ws + (size_t)BATCH * KDIM / 2;   // 8 MiB (24 MiB ws)

    pack_x4<<<(BATCH * (size_t)KDIM / 8) / 256, 256, 0, stream>>>(x, (uint32_t*)xb);
    pack_w4<<<((size_t)NOUT * KDIM / 8) / 256, 256, 0, stream>>>(W, (uint32_t*)wb);

    dim3 grid(NOUT / 256, BATCH / 256);   // (16, 32) = 512 blocks
    bin_gemm4<<<grid, 512, 0, stream>>>(xb, wb, out);
}